// Round 1
// baseline (478.942 us; speedup 1.0000x reference)
//
#include <hip/hip_runtime.h>
#include <hip/hip_bf16.h>

// Problem shape (from reference setup_inputs): img (1, X=192, Y=192, Z=48, C=64) fp32,
// rois (1, R=64, 6) int32 (x, y, z, w, h, d), pool_size P=7, out (1, R, P, P, C) fp32.
#define XD 192
#define YD 192
#define ZD 48
#define CD 64
#define PP 7

__global__ __launch_bounds__(64) void roi_pool_kernel(
    const float* __restrict__ img,
    const int* __restrict__ rois,
    float* __restrict__ out) {
  const int c = threadIdx.x;            // channel lane 0..63
  int bid = blockIdx.x;                 // r * P * P + px * P + py
  const int py = bid % PP; bid /= PP;
  const int px = bid % PP; bid /= PP;
  const int r = bid;

  const int* roi = rois + r * 6;
  const int x = roi[0];
  const int y = roi[1];
  const int z = roi[2];
  const int w = roi[3];
  const int h = roi[4];

  // Match reference math exactly (fp32, same op order):
  // sx = px * (w / P); x0 = floor(sx); fx = sx - x0
  const float sxv = (float)px * ((float)w / 7.0f);
  const float syv = (float)py * ((float)h / 7.0f);
  const int x0 = (int)floorf(sxv);
  const int y0 = (int)floorf(syv);
  const float fx = sxv - (float)x0;
  const float fy = syv - (float)y0;

  // clamp within crop, offset into volume, clamp to bounds
  int x0c = min(max(x0, 0), w - 1);
  int x1c = min(max(x0 + 1, 0), w - 1);
  int y0c = min(max(y0, 0), h - 1);
  int y1c = min(max(y0 + 1, 0), h - 1);
  const int x0a = min(max(x + x0c, 0), XD - 1);
  const int x1a = min(max(x + x1c, 0), XD - 1);
  const int y0a = min(max(y + y0c, 0), YD - 1);
  const int y1a = min(max(y + y1c, 0), YD - 1);
  const int zc  = min(max(z, 0), ZD - 1);

  // index = ((xi*Y + yi)*Z + z)*C + c
  const long long base00 = ((long long)(x0a * YD + y0a) * ZD + zc) * CD + c;
  const long long base10 = ((long long)(x1a * YD + y0a) * ZD + zc) * CD + c;
  const long long base01 = ((long long)(x0a * YD + y1a) * ZD + zc) * CD + c;
  const long long base11 = ((long long)(x1a * YD + y1a) * ZD + zc) * CD + c;

  const float v00 = img[base00];
  const float v10 = img[base10];
  const float v01 = img[base01];
  const float v11 = img[base11];

  const float res = v00 * (1.0f - fx) * (1.0f - fy)
                  + v10 * fx * (1.0f - fy)
                  + v01 * (1.0f - fx) * fy
                  + v11 * fx * fy;

  // out[r][px][py][c]
  out[(((r * PP + px) * PP) + py) * CD + c] = res;
}

extern "C" void kernel_launch(void* const* d_in, const int* in_sizes, int n_in,
                              void* d_out, int out_size, void* d_ws, size_t ws_size,
                              hipStream_t stream) {
  const float* img  = (const float*)d_in[0];
  const int*   rois = (const int*)d_in[1];
  // d_in[2] is pool_size (=7); shape constants are compile-time.
  float* out = (float*)d_out;

  const int R = in_sizes[1] / 6;        // 64
  const int nblocks = R * PP * PP;      // 3136
  roi_pool_kernel<<<nblocks, 64, 0, stream>>>(img, rois, out);
}